// Round 13
// baseline (105.859 us; speedup 1.0000x reference)
//
#include <hip/hip_runtime.h>
#include <hip/hip_bf16.h>
#include <stdint.h>

#define TOKENS 16384   // N=4 * L=4096
#define LSEQ 4096
#define WPAD 72        // padded row length (shorts) for M/vw/U tiles

typedef short bf16x8 __attribute__((ext_vector_type(8)));
typedef float f32x4 __attribute__((ext_vector_type(4)));

typedef __attribute__((address_space(1))) void as1_t;
typedef __attribute__((address_space(3))) void as3_t;

__device__ __forceinline__ unsigned short f2bf(float x) {
  __hip_bfloat16 t = __float2bfloat16(x);
  return *reinterpret_cast<unsigned short*>(&t);
}

__device__ __forceinline__ bf16x8 pack8(float4 a, float4 b) {
  bf16x8 t;
  t[0] = (short)f2bf(a.x); t[1] = (short)f2bf(a.y);
  t[2] = (short)f2bf(a.z); t[3] = (short)f2bf(a.w);
  t[4] = (short)f2bf(b.x); t[5] = (short)f2bf(b.y);
  t[6] = (short)f2bf(b.z); t[7] = (short)f2bf(b.w);
  return t;
}

__device__ __forceinline__ void async16(const void* g, void* lds) {
  __builtin_amdgcn_global_load_lds((as1_t*)const_cast<void*>(g),
                                   (as3_t*)lds, 16, 0, 0);
}
#define WAITCNT(n) asm volatile("s_waitcnt vmcnt(" #n ")" ::: "memory")

// ---------------- prep: M[f][e] = sum_d qw[d][f]*kw[d][e]; vw -> bf16 (1 block) -------
__global__ __launch_bounds__(1024) void prep_weights(
    const float* __restrict__ qw, const float* __restrict__ kw,
    const float* __restrict__ vw, unsigned short* __restrict__ Mout,
    unsigned short* __restrict__ vwout) {
  __shared__ float ql[4096], kl[4096];
  const int t = threadIdx.x;
  ((float4*)ql)[t] = ((const float4*)qw)[t];
  ((float4*)kl)[t] = ((const float4*)kw)[t];
  {
    float4 f = ((const float4*)vw)[t];
    union { unsigned short us[4]; uint2 u2; } pk;
    pk.us[0] = f2bf(f.x); pk.us[1] = f2bf(f.y);
    pk.us[2] = f2bf(f.z); pk.us[3] = f2bf(f.w);
    ((uint2*)vwout)[t] = pk.u2;
  }
  __syncthreads();
  const int f = t >> 4;            // 0..63  (q raw dim)
  const int e0 = (t & 15) * 4;     // 0..60  (k raw dim block)
  float acc0 = 0.f, acc1 = 0.f, acc2 = 0.f, acc3 = 0.f;
#pragma unroll 8
  for (int d = 0; d < 64; ++d) {
    const float qv = ql[d * 64 + f];
    const float4 kv = *(const float4*)&kl[d * 64 + e0];
    acc0 += qv * kv.x; acc1 += qv * kv.y; acc2 += qv * kv.z; acc3 += qv * kv.w;
  }
  union { unsigned short us[4]; uint2 u2; } pk;
  pk.us[0] = f2bf(acc0); pk.us[1] = f2bf(acc1);
  pk.us[2] = f2bf(acc2); pk.us[3] = f2bf(acc3);
  *(uint2*)&Mout[f * 64 + e0] = pk.u2;
}

// ---------- attn (blocks 0..1023, 16 waves = 16 tokens) + fc_w cvt (blocks 1024..1279) -
// attn math identical to R11/attn11 (HW-validated): S^T = (Rk@M^T)@Rq^T; v4 = Rv@vw^T;
// O = P@v4. mfma(fragA(X), fragA(Y)) = X @ Y^T; fragA lane: X[row=l&15][k=(l>>4)*8+j];
// C: col=l&15, row=(l>>4)*4+r. 16-wave blocks cut weight-staging traffic 64->16 MiB.
__global__ __launch_bounds__(1024) void attn_cvt(
    const float* __restrict__ q, const float* __restrict__ k,
    const float* __restrict__ v, const int* __restrict__ mask,
    const unsigned short* __restrict__ Mg, const unsigned short* __restrict__ vwg,
    unsigned short* __restrict__ X,
    const float* __restrict__ fcw, unsigned short* __restrict__ Wb) {
  __shared__ unsigned short Ml[64 * WPAD];        // 9216 B
  __shared__ unsigned short Vw[64 * WPAD];        // 9216 B
  __shared__ unsigned short scr[16][16 * WPAD];   // 32768 B  (total 51200)

  const int b = blockIdx.x;
  const int tid = threadIdx.x;

  if (b >= 1024) {  // ---- fc_w f32 -> bf16 (256 blocks x 1024 threads) ----
    const int i = (b - 1024) * 1024 + tid;
    float4 f = ((const float4*)fcw)[i];
    union { unsigned short us[4]; uint2 u2; } pk;
    pk.us[0] = f2bf(f.x); pk.us[1] = f2bf(f.y);
    pk.us[2] = f2bf(f.z); pk.us[3] = f2bf(f.w);
    ((uint2*)Wb)[i] = pk.u2;
    return;
  }

  const int l = tid & 63, w = tid >> 6;      // w: 0..15
  const int lr = l & 15, lg = l >> 4;

  const int tok = b * 16 + w;
  const size_t tb = (size_t)tok * 1024;
  const int off = lr * 64 + lg * 8;

  // ---- issue data loads first (long pole) ----
  const float4 qa = *(const float4*)(q + tb + off);
  const float4 qb = *(const float4*)(q + tb + off + 4);
  const float4 qc = *(const float4*)(q + tb + off + 32);
  const float4 qd = *(const float4*)(q + tb + off + 36);
  const float4 ka = *(const float4*)(k + tb + off);
  const float4 kb = *(const float4*)(k + tb + off + 4);
  const float4 kc = *(const float4*)(k + tb + off + 32);
  const float4 kd = *(const float4*)(k + tb + off + 36);
  const float4 va = *(const float4*)(v + tb + off);
  const float4 vb = *(const float4*)(v + tb + off + 4);
  const float4 vc = *(const float4*)(v + tb + off + 32);
  const float4 vd = *(const float4*)(v + tb + off + 36);
  const int4 mk4 = *(const int4*)(mask + (size_t)tok * 256 + lr * 16 + lg * 4);

  // ---- stage weights into LDS: 1024 threads, one uint4 each ----
  {
    const int row = (tid & 511) >> 3, c0 = (tid & 7) * 8;
    if (tid < 512)
      *(uint4*)&Ml[row * WPAD + c0] = *(const uint4*)(Mg + row * 64 + c0);
    else
      *(uint4*)&Vw[row * WPAD + c0] = *(const uint4*)(vwg + row * 64 + c0);
  }
  __syncthreads();

  // ---- pack raw fragments ----
  const bf16x8 ak0 = pack8(ka, kb), ak1 = pack8(kc, kd);
  const bf16x8 av0 = pack8(va, vb), av1 = pack8(vc, vd);
  const bf16x8 aq0 = pack8(qa, qb), aq1 = pack8(qc, qd);

  // ---- U = Rk @ M^T ; v4 = Rv @ vw^T ----
  f32x4 accu[4], accv[4];
#pragma unroll
  for (int n = 0; n < 4; ++n) {
    const int wrow = (n * 16 + lr) * WPAD;
    f32x4 z = {};
    const bf16x8 bm0 = *(const bf16x8*)&Ml[wrow + lg * 8];
    const bf16x8 bm1 = *(const bf16x8*)&Ml[wrow + 32 + lg * 8];
    accu[n] = __builtin_amdgcn_mfma_f32_16x16x32_bf16(ak0, bm0, z, 0, 0, 0);
    accu[n] = __builtin_amdgcn_mfma_f32_16x16x32_bf16(ak1, bm1, accu[n], 0, 0, 0);
    const bf16x8 bw0 = *(const bf16x8*)&Vw[wrow + lg * 8];
    const bf16x8 bw1 = *(const bf16x8*)&Vw[wrow + 32 + lg * 8];
    accv[n] = __builtin_amdgcn_mfma_f32_16x16x32_bf16(av0, bw0, z, 0, 0, 0);
    accv[n] = __builtin_amdgcn_mfma_f32_16x16x32_bf16(av1, bw1, accv[n], 0, 0, 0);
  }

  // ---- spill U (row-major [g][e]) to wave-private LDS ----
  unsigned short* U = scr[w];
#pragma unroll
  for (int n = 0; n < 4; ++n)
#pragma unroll
    for (int r = 0; r < 4; ++r)
      U[(lg * 4 + r) * WPAD + n * 16 + lr] = f2bf(accu[n][r]);

  // ---- S^T = U @ Rq^T ----
  const bf16x8 ua0 = *(const bf16x8*)&U[lr * WPAD + lg * 8];
  const bf16x8 ua1 = *(const bf16x8*)&U[lr * WPAD + 32 + lg * 8];
  f32x4 z4 = {};
  f32x4 st = __builtin_amdgcn_mfma_f32_16x16x32_bf16(ua0, aq0, z4, 0, 0, 0);
  st = __builtin_amdgcn_mfma_f32_16x16x32_bf16(ua1, aq1, st, 0, 0, 0);

  // ---- softmax over g (no max-subtraction; masked -> 0) ----
  float e[4];
  float sm = 0.f;
  const int mks[4] = {mk4.x, mk4.y, mk4.z, mk4.w};
#pragma unroll
  for (int r = 0; r < 4; ++r) {
    e[r] = (mks[r] != 0) ? __expf(st[r] * 0.125f) : 0.f;
    sm += e[r];
  }
  sm += __shfl_xor(sm, 16);
  sm += __shfl_xor(sm, 32);
  const float inv = 1.0f / sm;
#pragma unroll
  for (int r = 0; r < 4; ++r) e[r] *= inv;

  // ---- PV A-frag (P[h=lr][g=lg*8+j], lanes lg>=2 zero) ----
  bf16x8 apv;
#pragma unroll
  for (int j = 0; j < 8; ++j) {
    const int srcg = (lg * 2 + (j >> 2)) & 3;
    const float pv = __shfl(e[j & 3], lr + srcg * 16, 64);
    apv[j] = (short)((lg < 2) ? f2bf(pv) : (unsigned short)0);
  }

  // ---- PV B-frags from accv via shuffles; O = P @ v4 ----
  const int s0 = lr + ((lg & 1) * 2) * 16;
  const int s1 = s0 + 16;
  f32x4 o[4];
#pragma unroll
  for (int n = 0; n < 4; ++n) {
    bf16x8 bv;
#pragma unroll
    for (int j = 0; j < 8; ++j) {
      const float xv = __shfl(accv[n][j & 3], (j < 4) ? s0 : s1, 64);
      bv[j] = (short)f2bf(xv);
    }
    f32x4 z = {};
    o[n] = __builtin_amdgcn_mfma_f32_16x16x32_bf16(apv, bv, z, 0, 0, 0);
  }

  // ---- transpose O through LDS (reuse U region), then vector stores ----
#pragma unroll
  for (int n = 0; n < 4; ++n)
#pragma unroll
    for (int r = 0; r < 4; ++r)
      U[(lg * 4 + r) * WPAD + n * 16 + lr] = f2bf(o[n][r]);

  const int nb = tok >> 12, lpos = tok & (LSEQ - 1);
#pragma unroll
  for (int it = 0; it < 2; ++it) {
    const int idx = it * 64 + l;
    const int h = idx >> 3, c = idx & 7;
    const uint4 val = *(const uint4*)&U[h * WPAD + c * 8];
    *(uint4*)&X[((size_t)(nb * 16 + h) * LSEQ + lpos) * 64 + c * 8] = val;
  }
}

// ---------------- final FC: 256^2-tile 8-wave phase-split (R12-validated) ----------------
__global__ __launch_bounds__(512, 1) void gemm_fc8(
    const unsigned short* __restrict__ A,
    const unsigned short* __restrict__ B,
    const float* __restrict__ bias,
    float* __restrict__ C) {
  __shared__ char lds[131072];

  const int tid = threadIdx.x;
  const int l = tid & 63;
  const int wv = tid >> 6;
  const int wr = wv >> 2;
  const int wc = wv & 3;
  const int lr = l & 15, lg = l >> 4;

  const int bid = blockIdx.x;
  const int wg = (bid & 7) * 32 + (bid >> 3);
  const int tm = (wg >> 2) * 256;
  const int tn = (wg & 3) * 256;

  const int srow = wv * 8 + (l >> 3);
  const int schunk = (l & 7) ^ (2 * ((l >> 5) & 1));

  auto stage_unit = [&](int u) {
    const int kt = u >> 2, t = u & 3, h = t & 1;
    const unsigned short* src =
        (t < 2) ? (A + (size_t)(tm + h * 128) * 1024)
                : (B + (size_t)(tn + h * 128) * 1024);
    const int k0 = kt * 64;
    char* dst = lds + (u & 7) * 16384 + wv * 1024;
#pragma unroll
    for (int li = 0; li < 2; ++li) {
      const int r = li * 64 + srow;
      async16(src + (size_t)r * 1024 + k0 + schunk * 8, dst + li * 8192);
    }
  };

#pragma unroll
  for (int u = 0; u < 4; ++u) stage_unit(u);
  WAITCNT(0);
  __builtin_amdgcn_s_barrier();

  f32x4 acc[8][4] = {};
  const int swz = ((lr >> 2) & 1) * 32;
  const int arow0 = lr * 128;
  const int brow0 = ((wc & 1) * 64 + lr) * 128;

#pragma unroll 1
  for (int j = 0; j < 16; ++j) {
    const char* abase = lds + ((j & 1) * 4 + wr) * 16384;
    const char* bbase = lds + ((j & 1) * 4 + 2 + (wc >> 1)) * 16384;
    bf16x8 bfr[4], af[4];

#pragma unroll
    for (int fj = 0; fj < 4; ++fj)
      bfr[fj] = *(const bf16x8*)(bbase + brow0 + fj * 2048 + ((lg * 16) ^ swz));
#pragma unroll
    for (int mi = 0; mi < 4; ++mi)
      af[mi] = *(const bf16x8*)(abase + arow0 + mi * 2048 + ((lg * 16) ^ swz));
    if (j < 15) stage_unit(4 * j + 4);
    __builtin_amdgcn_sched_barrier(0);
    __builtin_amdgcn_s_barrier();
    __builtin_amdgcn_s_setprio(1);
#pragma unroll
    for (int mi = 0; mi < 4; ++mi)
#pragma unroll
      for (int fj = 0; fj < 4; ++fj)
        acc[mi][fj] = __builtin_amdgcn_mfma_f32_16x16x32_bf16(af[mi], bfr[fj],
                                                              acc[mi][fj], 0, 0, 0);
    __builtin_amdgcn_s_setprio(0);
    __builtin_amdgcn_s_barrier();

#pragma unroll
    for (int mi = 0; mi < 4; ++mi)
      af[mi] = *(const bf16x8*)(abase + arow0 + 8192 + mi * 2048 + ((lg * 16) ^ swz));
    if (j < 15) stage_unit(4 * j + 5);
    __builtin_amdgcn_sched_barrier(0);
    __builtin_amdgcn_s_barrier();
    __builtin_amdgcn_s_setprio(1);
#pragma unroll
    for (int mi = 0; mi < 4; ++mi)
#pragma unroll
      for (int fj = 0; fj < 4; ++fj)
        acc[4 + mi][fj] = __builtin_amdgcn_mfma_f32_16x16x32_bf16(af[mi], bfr[fj],
                                                                  acc[4 + mi][fj], 0, 0, 0);
    __builtin_amdgcn_s_setprio(0);
    __builtin_amdgcn_s_barrier();

#pragma unroll
    for (int fj = 0; fj < 4; ++fj)
      bfr[fj] = *(const bf16x8*)(bbase + brow0 + fj * 2048 + ((64 + lg * 16) ^ swz));
#pragma unroll
    for (int mi = 0; mi < 4; ++mi)
      af[mi] = *(const bf16x8*)(abase + arow0 + mi * 2048 + ((64 + lg * 16) ^ swz));
    if (j < 15) stage_unit(4 * j + 6);
    __builtin_amdgcn_sched_barrier(0);
    __builtin_amdgcn_s_barrier();
    __builtin_amdgcn_s_setprio(1);
#pragma unroll
    for (int mi = 0; mi < 4; ++mi)
#pragma unroll
      for (int fj = 0; fj < 4; ++fj)
        acc[mi][fj] = __builtin_amdgcn_mfma_f32_16x16x32_bf16(af[mi], bfr[fj],
                                                              acc[mi][fj], 0, 0, 0);
    __builtin_amdgcn_s_setprio(0);
    __builtin_amdgcn_s_barrier();

#pragma unroll
    for (int mi = 0; mi < 4; ++mi)
      af[mi] = *(const bf16x8*)(abase + arow0 + 8192 + mi * 2048 + ((64 + lg * 16) ^ swz));
    if (j < 15) stage_unit(4 * j + 7);
    __builtin_amdgcn_sched_barrier(0);
    __builtin_amdgcn_s_barrier();
    __builtin_amdgcn_s_setprio(1);
#pragma unroll
    for (int mi = 0; mi < 4; ++mi)
#pragma unroll
      for (int fj = 0; fj < 4; ++fj)
        acc[4 + mi][fj] = __builtin_amdgcn_mfma_f32_16x16x32_bf16(af[mi], bfr[fj],
                                                                  acc[4 + mi][fj], 0, 0, 0);
    __builtin_amdgcn_s_setprio(0);
    if (j < 15) {
      WAITCNT(0);
      __builtin_amdgcn_s_barrier();
    }
  }

#pragma unroll
  for (int fj = 0; fj < 4; ++fj) {
    const int col = tn + wc * 64 + fj * 16 + lr;
    const float bv = bias[col];
#pragma unroll
    for (int mf = 0; mf < 8; ++mf)
#pragma unroll
      for (int rr = 0; rr < 4; ++rr) {
        const int row = tm + wr * 128 + mf * 16 + lg * 4 + rr;
        C[(size_t)row * 1024 + col] = acc[mf][fj][rr] + bv;
      }
  }
}

extern "C" void kernel_launch(void* const* d_in, const int* in_sizes, int n_in,
                              void* d_out, int out_size, void* d_ws, size_t ws_size,
                              hipStream_t stream) {
  (void)in_sizes; (void)n_in; (void)out_size; (void)ws_size;
  const float* q   = (const float*)d_in[0];
  const float* k   = (const float*)d_in[1];
  const float* v   = (const float*)d_in[2];
  const int*  mask = (const int*)d_in[3];
  const float* qw  = (const float*)d_in[4];
  const float* kw  = (const float*)d_in[5];
  const float* vw  = (const float*)d_in[6];
  const float* fcw = (const float*)d_in[7];
  const float* fcb = (const float*)d_in[8];
  float* out = (float*)d_out;

  unsigned short* X   = (unsigned short*)d_ws;            // 16M bf16 = 32 MiB
  unsigned short* Wb  = X + (size_t)16 * 1024 * 1024;     // 1M bf16  =  2 MiB
  unsigned short* Mw  = Wb + (size_t)1024 * 1024;         // 4096 bf16 = 8 KiB
  unsigned short* vwb = Mw + 4096;                        // 4096 bf16 = 8 KiB

  prep_weights<<<dim3(1), dim3(1024), 0, stream>>>(qw, kw, vw, Mw, vwb);
  attn_cvt<<<dim3(1280), dim3(1024), 0, stream>>>(q, k, v, mask, Mw, vwb, X, fcw, Wb);
  gemm_fc8<<<dim3(256), dim3(512), 0, stream>>>(X, Wb, fcb, out);
}

// Round 14
// 102.218 us; speedup vs baseline: 1.0356x; 1.0356x over previous
//
#include <hip/hip_runtime.h>
#include <hip/hip_bf16.h>
#include <stdint.h>

#define TOKENS 16384   // N=4 * L=4096
#define LSEQ 4096
#define WPAD 72        // padded row length (shorts) for M/vw/U tiles

typedef short bf16x8 __attribute__((ext_vector_type(8)));
typedef float f32x4 __attribute__((ext_vector_type(4)));

typedef __attribute__((address_space(1))) void as1_t;
typedef __attribute__((address_space(3))) void as3_t;

__device__ __forceinline__ unsigned short f2bf(float x) {
  __hip_bfloat16 t = __float2bfloat16(x);
  return *reinterpret_cast<unsigned short*>(&t);
}

__device__ __forceinline__ bf16x8 pack8(float4 a, float4 b) {
  bf16x8 t;
  t[0] = (short)f2bf(a.x); t[1] = (short)f2bf(a.y);
  t[2] = (short)f2bf(a.z); t[3] = (short)f2bf(a.w);
  t[4] = (short)f2bf(b.x); t[5] = (short)f2bf(b.y);
  t[6] = (short)f2bf(b.z); t[7] = (short)f2bf(b.w);
  return t;
}

__device__ __forceinline__ void async16(const void* g, void* lds) {
  __builtin_amdgcn_global_load_lds((as1_t*)const_cast<void*>(g),
                                   (as3_t*)lds, 16, 0, 0);
}
#define WAITCNT(n) asm volatile("s_waitcnt vmcnt(" #n ")" ::: "memory")

// ---------------- merged: fc_w -> bf16 (blocks 0..1023) + weight prep (block 1024) ----
__global__ __launch_bounds__(256) void cvt_prep(
    const float* __restrict__ fcw, unsigned short* __restrict__ Wb,
    const float* __restrict__ qw, const float* __restrict__ kw,
    const float* __restrict__ vw, unsigned short* __restrict__ Mout,
    unsigned short* __restrict__ vwout) {
  const int b = blockIdx.x, t = threadIdx.x;
  if (b < 1024) {
    const int i = b * 256 + t;
    float4 f = ((const float4*)fcw)[i];
    union { unsigned short us[4]; uint2 u2; } pk;
    pk.us[0] = f2bf(f.x); pk.us[1] = f2bf(f.y);
    pk.us[2] = f2bf(f.z); pk.us[3] = f2bf(f.w);
    ((uint2*)Wb)[i] = pk.u2;
    return;
  }
  __shared__ float ql[4096], kl[4096];
#pragma unroll
  for (int j = 0; j < 4; ++j) {
    const int i = t + j * 256;
    ((float4*)ql)[i] = ((const float4*)qw)[i];
    ((float4*)kl)[i] = ((const float4*)kw)[i];
    float4 f = ((const float4*)vw)[i];
    union { unsigned short us[4]; uint2 u2; } pk;
    pk.us[0] = f2bf(f.x); pk.us[1] = f2bf(f.y);
    pk.us[2] = f2bf(f.z); pk.us[3] = f2bf(f.w);
    ((uint2*)vwout)[i] = pk.u2;
  }
  __syncthreads();
  const int f = t >> 2;            // 0..63
  const int e0 = (t & 3) * 16;     // 0,16,32,48
  float4 a0 = {}, a1 = {}, a2 = {}, a3 = {};
#pragma unroll 8
  for (int d = 0; d < 64; ++d) {
    const float qv = ql[d * 64 + f];
    const float* kr = &kl[d * 64 + e0];
    const float4 k0 = *(const float4*)(kr);
    const float4 k1 = *(const float4*)(kr + 4);
    const float4 k2 = *(const float4*)(kr + 8);
    const float4 k3 = *(const float4*)(kr + 12);
    a0.x += qv * k0.x; a0.y += qv * k0.y; a0.z += qv * k0.z; a0.w += qv * k0.w;
    a1.x += qv * k1.x; a1.y += qv * k1.y; a1.z += qv * k1.z; a1.w += qv * k1.w;
    a2.x += qv * k2.x; a2.y += qv * k2.y; a2.z += qv * k2.z; a2.w += qv * k2.w;
    a3.x += qv * k3.x; a3.y += qv * k3.y; a3.z += qv * k3.z; a3.w += qv * k3.w;
  }
  union { unsigned short us[8]; uint4 u4; } p0, p1;
  p0.us[0] = f2bf(a0.x); p0.us[1] = f2bf(a0.y); p0.us[2] = f2bf(a0.z); p0.us[3] = f2bf(a0.w);
  p0.us[4] = f2bf(a1.x); p0.us[5] = f2bf(a1.y); p0.us[6] = f2bf(a1.z); p0.us[7] = f2bf(a1.w);
  p1.us[0] = f2bf(a2.x); p1.us[1] = f2bf(a2.y); p1.us[2] = f2bf(a2.z); p1.us[3] = f2bf(a2.w);
  p1.us[4] = f2bf(a3.x); p1.us[5] = f2bf(a3.y); p1.us[6] = f2bf(a3.z); p1.us[7] = f2bf(a3.w);
  *(uint4*)&Mout[f * 64 + e0] = p0.u4;
  *(uint4*)&Mout[f * 64 + e0 + 8] = p1.u4;
}

// ---------------- fused attention: R11 (empirical ceiling ~78-83 us) ----------------
__global__ __launch_bounds__(256, 6) void attn11(
    const float* __restrict__ q, const float* __restrict__ k,
    const float* __restrict__ v, const int* __restrict__ mask,
    const unsigned short* __restrict__ Mg, const unsigned short* __restrict__ vwg,
    unsigned short* __restrict__ X) {
  __shared__ unsigned short Ml[64 * WPAD];
  __shared__ unsigned short Vw[64 * WPAD];
  __shared__ unsigned short scr[4][16 * WPAD];

  const int tid = threadIdx.x;
  const int l = tid & 63, w = tid >> 6;
  const int lr = l & 15, lg = l >> 4;

  const int tok = blockIdx.x * 4 + w;
  const size_t tb = (size_t)tok * 1024;
  const int off = lr * 64 + lg * 8;

  const float4 qa = *(const float4*)(q + tb + off);
  const float4 qb = *(const float4*)(q + tb + off + 4);
  const float4 qc = *(const float4*)(q + tb + off + 32);
  const float4 qd = *(const float4*)(q + tb + off + 36);
  const float4 ka = *(const float4*)(k + tb + off);
  const float4 kb = *(const float4*)(k + tb + off + 4);
  const float4 kc = *(const float4*)(k + tb + off + 32);
  const float4 kd = *(const float4*)(k + tb + off + 36);
  const float4 va = *(const float4*)(v + tb + off);
  const float4 vb = *(const float4*)(v + tb + off + 4);
  const float4 vc = *(const float4*)(v + tb + off + 32);
  const float4 vd = *(const float4*)(v + tb + off + 36);
  const int4 mk4 = *(const int4*)(mask + (size_t)tok * 256 + lr * 16 + lg * 4);

  {
    const int row = tid >> 2, c0 = (tid & 3) * 16;
    *(uint4*)&Ml[row * WPAD + c0]     = *(const uint4*)(Mg + row * 64 + c0);
    *(uint4*)&Ml[row * WPAD + c0 + 8] = *(const uint4*)(Mg + row * 64 + c0 + 8);
    *(uint4*)&Vw[row * WPAD + c0]     = *(const uint4*)(vwg + row * 64 + c0);
    *(uint4*)&Vw[row * WPAD + c0 + 8] = *(const uint4*)(vwg + row * 64 + c0 + 8);
  }
  __syncthreads();

  const bf16x8 ak0 = pack8(ka, kb), ak1 = pack8(kc, kd);
  const bf16x8 av0 = pack8(va, vb), av1 = pack8(vc, vd);
  const bf16x8 aq0 = pack8(qa, qb), aq1 = pack8(qc, qd);

  f32x4 accu[4], accv[4];
#pragma unroll
  for (int n = 0; n < 4; ++n) {
    const int wrow = (n * 16 + lr) * WPAD;
    f32x4 z = {};
    const bf16x8 bm0 = *(const bf16x8*)&Ml[wrow + lg * 8];
    const bf16x8 bm1 = *(const bf16x8*)&Ml[wrow + 32 + lg * 8];
    accu[n] = __builtin_amdgcn_mfma_f32_16x16x32_bf16(ak0, bm0, z, 0, 0, 0);
    accu[n] = __builtin_amdgcn_mfma_f32_16x16x32_bf16(ak1, bm1, accu[n], 0, 0, 0);
    const bf16x8 bw0 = *(const bf16x8*)&Vw[wrow + lg * 8];
    const bf16x8 bw1 = *(const bf16x8*)&Vw[wrow + 32 + lg * 8];
    accv[n] = __builtin_amdgcn_mfma_f32_16x16x32_bf16(av0, bw0, z, 0, 0, 0);
    accv[n] = __builtin_amdgcn_mfma_f32_16x16x32_bf16(av1, bw1, accv[n], 0, 0, 0);
  }

  unsigned short* U = scr[w];
#pragma unroll
  for (int n = 0; n < 4; ++n)
#pragma unroll
    for (int r = 0; r < 4; ++r)
      U[(lg * 4 + r) * WPAD + n * 16 + lr] = f2bf(accu[n][r]);

  const bf16x8 ua0 = *(const bf16x8*)&U[lr * WPAD + lg * 8];
  const bf16x8 ua1 = *(const bf16x8*)&U[lr * WPAD + 32 + lg * 8];
  f32x4 z4 = {};
  f32x4 st = __builtin_amdgcn_mfma_f32_16x16x32_bf16(ua0, aq0, z4, 0, 0, 0);
  st = __builtin_amdgcn_mfma_f32_16x16x32_bf16(ua1, aq1, st, 0, 0, 0);

  float e[4];
  float sm = 0.f;
  const int mks[4] = {mk4.x, mk4.y, mk4.z, mk4.w};
#pragma unroll
  for (int r = 0; r < 4; ++r) {
    e[r] = (mks[r] != 0) ? __expf(st[r] * 0.125f) : 0.f;
    sm += e[r];
  }
  sm += __shfl_xor(sm, 16);
  sm += __shfl_xor(sm, 32);
  const float inv = 1.0f / sm;
#pragma unroll
  for (int r = 0; r < 4; ++r) e[r] *= inv;

  bf16x8 apv;
#pragma unroll
  for (int j = 0; j < 8; ++j) {
    const int srcg = (lg * 2 + (j >> 2)) & 3;
    const float pv = __shfl(e[j & 3], lr + srcg * 16, 64);
    apv[j] = (short)((lg < 2) ? f2bf(pv) : (unsigned short)0);
  }

  const int s0 = lr + ((lg & 1) * 2) * 16;
  const int s1 = s0 + 16;
  f32x4 o[4];
#pragma unroll
  for (int n = 0; n < 4; ++n) {
    bf16x8 bv;
#pragma unroll
    for (int j = 0; j < 8; ++j) {
      const float xv = __shfl(accv[n][j & 3], (j < 4) ? s0 : s1, 64);
      bv[j] = (short)f2bf(xv);
    }
    f32x4 z = {};
    o[n] = __builtin_amdgcn_mfma_f32_16x16x32_bf16(apv, bv, z, 0, 0, 0);
  }

#pragma unroll
  for (int n = 0; n < 4; ++n)
#pragma unroll
    for (int r = 0; r < 4; ++r)
      U[(lg * 4 + r) * WPAD + n * 16 + lr] = f2bf(o[n][r]);

  const int nb = tok >> 12, lpos = tok & (LSEQ - 1);
#pragma unroll
  for (int it = 0; it < 2; ++it) {
    const int idx = it * 64 + l;
    const int h = idx >> 3, c = idx & 7;
    const uint4 val = *(const uint4*)&U[h * WPAD + c * 8];
    *(uint4*)&X[((size_t)(nb * 16 + h) * LSEQ + lpos) * 64 + c * 8] = val;
  }
}

// ---------------- final FC: 256^2-tile 8-wave phase-split (R12-validated) ----------------
__global__ __launch_bounds__(512, 1) void gemm_fc8(
    const unsigned short* __restrict__ A,
    const unsigned short* __restrict__ B,
    const float* __restrict__ bias,
    float* __restrict__ C) {
  __shared__ char lds[131072];

  const int tid = threadIdx.x;
  const int l = tid & 63;
  const int wv = tid >> 6;
  const int wr = wv >> 2;
  const int wc = wv & 3;
  const int lr = l & 15, lg = l >> 4;

  const int bid = blockIdx.x;
  const int wg = (bid & 7) * 32 + (bid >> 3);
  const int tm = (wg >> 2) * 256;
  const int tn = (wg & 3) * 256;

  const int srow = wv * 8 + (l >> 3);
  const int schunk = (l & 7) ^ (2 * ((l >> 5) & 1));

  auto stage_unit = [&](int u) {
    const int kt = u >> 2, t = u & 3, h = t & 1;
    const unsigned short* src =
        (t < 2) ? (A + (size_t)(tm + h * 128) * 1024)
                : (B + (size_t)(tn + h * 128) * 1024);
    const int k0 = kt * 64;
    char* dst = lds + (u & 7) * 16384 + wv * 1024;
#pragma unroll
    for (int li = 0; li < 2; ++li) {
      const int r = li * 64 + srow;
      async16(src + (size_t)r * 1024 + k0 + schunk * 8, dst + li * 8192);
    }
  };

#pragma unroll
  for (int u = 0; u < 4; ++u) stage_unit(u);
  WAITCNT(0);
  __builtin_amdgcn_s_barrier();

  f32x4 acc[8][4] = {};
  const int swz = ((lr >> 2) & 1) * 32;
  const int arow0 = lr * 128;
  const int brow0 = ((wc & 1) * 64 + lr) * 128;

#pragma unroll 1
  for (int j = 0; j < 16; ++j) {
    const char* abase = lds + ((j & 1) * 4 + wr) * 16384;
    const char* bbase = lds + ((j & 1) * 4 + 2 + (wc >> 1)) * 16384;
    bf16x8 bfr[4], af[4];

#pragma unroll
    for (int fj = 0; fj < 4; ++fj)
      bfr[fj] = *(const bf16x8*)(bbase + brow0 + fj * 2048 + ((lg * 16) ^ swz));
#pragma unroll
    for (int mi = 0; mi < 4; ++mi)
      af[mi] = *(const bf16x8*)(abase + arow0 + mi * 2048 + ((lg * 16) ^ swz));
    if (j < 15) stage_unit(4 * j + 4);
    __builtin_amdgcn_sched_barrier(0);
    __builtin_amdgcn_s_barrier();
    __builtin_amdgcn_s_setprio(1);
#pragma unroll
    for (int mi = 0; mi < 4; ++mi)
#pragma unroll
      for (int fj = 0; fj < 4; ++fj)
        acc[mi][fj] = __builtin_amdgcn_mfma_f32_16x16x32_bf16(af[mi], bfr[fj],
                                                              acc[mi][fj], 0, 0, 0);
    __builtin_amdgcn_s_setprio(0);
    __builtin_amdgcn_s_barrier();

#pragma unroll
    for (int mi = 0; mi < 4; ++mi)
      af[mi] = *(const bf16x8*)(abase + arow0 + 8192 + mi * 2048 + ((lg * 16) ^ swz));
    if (j < 15) stage_unit(4 * j + 5);
    __builtin_amdgcn_sched_barrier(0);
    __builtin_amdgcn_s_barrier();
    __builtin_amdgcn_s_setprio(1);
#pragma unroll
    for (int mi = 0; mi < 4; ++mi)
#pragma unroll
      for (int fj = 0; fj < 4; ++fj)
        acc[4 + mi][fj] = __builtin_amdgcn_mfma_f32_16x16x32_bf16(af[mi], bfr[fj],
                                                                  acc[4 + mi][fj], 0, 0, 0);
    __builtin_amdgcn_s_setprio(0);
    __builtin_amdgcn_s_barrier();

#pragma unroll
    for (int fj = 0; fj < 4; ++fj)
      bfr[fj] = *(const bf16x8*)(bbase + brow0 + fj * 2048 + ((64 + lg * 16) ^ swz));
#pragma unroll
    for (int mi = 0; mi < 4; ++mi)
      af[mi] = *(const bf16x8*)(abase + arow0 + mi * 2048 + ((64 + lg * 16) ^ swz));
    if (j < 15) stage_unit(4 * j + 6);
    __builtin_amdgcn_sched_barrier(0);
    __builtin_amdgcn_s_barrier();
    __builtin_amdgcn_s_setprio(1);
#pragma unroll
    for (int mi = 0; mi < 4; ++mi)
#pragma unroll
      for (int fj = 0; fj < 4; ++fj)
        acc[mi][fj] = __builtin_amdgcn_mfma_f32_16x16x32_bf16(af[mi], bfr[fj],
                                                              acc[mi][fj], 0, 0, 0);
    __builtin_amdgcn_s_setprio(0);
    __builtin_amdgcn_s_barrier();

#pragma unroll
    for (int mi = 0; mi < 4; ++mi)
      af[mi] = *(const bf16x8*)(abase + arow0 + 8192 + mi * 2048 + ((64 + lg * 16) ^ swz));
    if (j < 15) stage_unit(4 * j + 7);
    __builtin_amdgcn_sched_barrier(0);
    __builtin_amdgcn_s_barrier();
    __builtin_amdgcn_s_setprio(1);
#pragma unroll
    for (int mi = 0; mi < 4; ++mi)
#pragma unroll
      for (int fj = 0; fj < 4; ++fj)
        acc[4 + mi][fj] = __builtin_amdgcn_mfma_f32_16x16x32_bf16(af[mi], bfr[fj],
                                                                  acc[4 + mi][fj], 0, 0, 0);
    __builtin_amdgcn_s_setprio(0);
    if (j < 15) {
      WAITCNT(0);
      __builtin_amdgcn_s_barrier();
    }
  }

#pragma unroll
  for (int fj = 0; fj < 4; ++fj) {
    const int col = tn + wc * 64 + fj * 16 + lr;
    const float bv = bias[col];
#pragma unroll
    for (int mf = 0; mf < 8; ++mf)
#pragma unroll
      for (int rr = 0; rr < 4; ++rr) {
        const int row = tm + wr * 128 + mf * 16 + lg * 4 + rr;
        C[(size_t)row * 1024 + col] = acc[mf][fj][rr] + bv;
      }
  }
}

extern "C" void kernel_launch(void* const* d_in, const int* in_sizes, int n_in,
                              void* d_out, int out_size, void* d_ws, size_t ws_size,
                              hipStream_t stream) {
  (void)in_sizes; (void)n_in; (void)out_size; (void)ws_size;
  const float* q   = (const float*)d_in[0];
  const float* k   = (const float*)d_in[1];
  const float* v   = (const float*)d_in[2];
  const int*  mask = (const int*)d_in[3];
  const float* qw  = (const float*)d_in[4];
  const float* kw  = (const float*)d_in[5];
  const float* vw  = (const float*)d_in[6];
  const float* fcw = (const float*)d_in[7];
  const float* fcb = (const float*)d_in[8];
  float* out = (float*)d_out;

  unsigned short* X   = (unsigned short*)d_ws;            // 16M bf16 = 32 MiB
  unsigned short* Wb  = X + (size_t)16 * 1024 * 1024;     // 1M bf16  =  2 MiB
  unsigned short* Mw  = Wb + (size_t)1024 * 1024;         // 4096 bf16 = 8 KiB
  unsigned short* vwb = Mw + 4096;                        // 4096 bf16 = 8 KiB

  cvt_prep<<<dim3(1025), dim3(256), 0, stream>>>(fcw, Wb, qw, kw, vw, Mw, vwb);
  attn11<<<dim3(4096), dim3(256), 0, stream>>>(q, k, v, mask, Mw, vwb, X);
  gemm_fc8<<<dim3(256), dim3(512), 0, stream>>>(X, Wb, fcb, out);
}